// Round 4
// baseline (85458.673 us; speedup 1.0000x reference)
//
#include <hip/hip_runtime.h>
#include <hip/hip_fp16.h>

#define HID   512
#define EMB   256
#define VOCAB 64
#define NL    2
#define BS    64
#define SLEN  128
#define LLEN  1024
#define G4    2048
#define NCH   4
#define NB    256
#define NT    512

typedef unsigned uu4 __attribute__((ext_vector_type(4)));

// ---------------------------------------------------------------------------
// MALL-coherent (write-through / cache-bypass) scalar access
__device__ __forceinline__ float ldv(const float* p) {
    return __hip_atomic_load(p, __ATOMIC_RELAXED, __HIP_MEMORY_SCOPE_AGENT);
}
__device__ __forceinline__ void stv(float* p, float v) {
    __hip_atomic_store(p, v, __ATOMIC_RELAXED, __HIP_MEMORY_SCOPE_AGENT);
}

// ---------------------------------------------------------------------------
struct SAttn {
    float u_s[512];
    float w_s[32];
    float msh[4];
    float accs[16][34];
    unsigned enc[32 * 261];
};
struct SCell { float red[8][10][66]; };
struct SLog  { float red[16 * 33]; };
union SMem { SAttn attn; SCell cell; SLog log; };

// ---------------------------------------------------------------------------
// relaxed grid barrier: no acquire/release (no L2 wb/inv). Ordering comes from
// the vmcnt(0) drain the compiler emits before s_barrier, plus MALL-coherent
// (sc0 sc1) data accesses everywhere across blocks.
__device__ __forceinline__ void gridbar(unsigned* bar, unsigned nb)
{
    __syncthreads();
    if (threadIdx.x == 0) {
        __hip_atomic_fetch_add(bar, 1u, __ATOMIC_RELAXED, __HIP_MEMORY_SCOPE_AGENT);
        while (__hip_atomic_load(bar, __ATOMIC_RELAXED, __HIP_MEMORY_SCOPE_AGENT)
               < nb * (unsigned)NB)
            __builtin_amdgcn_s_sleep(8);
    }
    __syncthreads();
}

// ---------------------------------------------------------------------------
// one-time kernels
__global__ __launch_bounds__(256)
void k_embed(const int* __restrict__ y, const float* __restrict__ emb,
             float* __restrict__ xembT)   // [t][e][b]
{
    int i = blockIdx.x * 256 + threadIdx.x;
    int b  = i & 63;
    int e  = (i >> 6) & 255;
    int ts = i >> 14;
    xembT[i] = emb[y[b * SLEN + ts] * EMB + e];
}

__global__ __launch_bounds__(256)
void k_cast(const float* __restrict__ src, __half* __restrict__ dst, int n4)
{
    int i = blockIdx.x * 256 + threadIdx.x;
    int stride = gridDim.x * 256;
    for (; i < n4; i += stride) {
        float4 v = reinterpret_cast<const float4*>(src)[i];
        reinterpret_cast<__half2*>(dst)[2 * i]     = __floats2half2_rn(v.x, v.y);
        reinterpret_cast<__half2*>(dst)[2 * i + 1] = __floats2half2_rn(v.z, v.w);
    }
}

__global__ __launch_bounds__(256)
void k_pmat(const float* __restrict__ Whw, const float* __restrict__ Wsw,
            const float* __restrict__ Wsb, float* __restrict__ P,
            float* __restrict__ p0)
{
    const int i = blockIdx.x;
    const int t = threadIdx.x;
    float a0 = 0.f, a1 = 0.f, ap = 0.f;
    for (int h = 0; h < HID; ++h) {
        float whi = Whw[h * HID + i];
        a0 += whi * Wsw[h * HID + t];
        a1 += whi * Wsw[h * HID + t + 256];
        ap += whi * Wsb[h];
    }
    P[i * HID + t]       = a0;
    P[i * HID + t + 256] = a1;
    if (t == 0) p0[i] = ap;
}

// ---------------------------------------------------------------------------
// batched-issue GEMV accumulate: load KW activations (transposed layout, lane=b)
// into registers back-to-back (deep vmcnt pipeline), then FMA against NR
// weight rows (cached float4 loads).
template<int KW, int NR, bool CACHED>
__device__ __forceinline__ void gacc(float* acc, const float* __restrict__ AT,
                                     const float* const* wp)
{
    float a[KW];
#pragma unroll
    for (int j = 0; j < KW; ++j)
        a[j] = CACHED ? AT[(size_t)j * 64] : ldv(AT + (size_t)j * 64);
#pragma unroll
    for (int j = 0; j < KW; j += 4) {
#pragma unroll
        for (int r = 0; r < NR; ++r) {
            float4 w = *reinterpret_cast<const float4*>(wp[r] + j);
            acc[r] += a[j] * w.x + a[j+1] * w.y + a[j+2] * w.z + a[j+3] * w.w;
        }
    }
}

// ---------------------------------------------------------------------------
// fused LSTM cell (2 h rows x 4 gates per block), optional fused hid rows
// (H-phase of previous step shares the ctx activation scan).
template<int KX, bool HASC, bool FUSE, bool XC>
__device__ __forceinline__ void phase_cell(SMem& sm, int i0,
    const float* __restrict__ xT, const float* __restrict__ cT,
    const float* __restrict__ hT,
    const float* __restrict__ Wih, int ldWih,
    const float* __restrict__ Whh, const float* __restrict__ W1,
    const float* __restrict__ bih, const float* __restrict__ bhh,
    float* cLds, float* hTout, const float* hpartLds, float* hidB)
{
    const int t = threadIdx.x;
    const int wv = t >> 6, lane = t & 63;
    float accG[8] = {};
    float accH[2] = {};
    {   // x part
        constexpr int KW = KX / 8;
        const int ks = wv * KW;
        const float* wp[8];
#pragma unroll
        for (int r = 0; r < 8; ++r)
            wp[r] = Wih + (size_t)((r & 3) * HID + i0 + (r >> 2)) * ldWih + ks;
        gacc<KW, 8, XC>(accG, xT + (size_t)ks * 64 + lane, wp);
    }
    if constexpr (HASC) {   // ctx part (+ fused hid rows of previous step's H)
        const int ks = wv * 64;
        float acc10[10];
#pragma unroll
        for (int r = 0; r < 8; ++r) acc10[r] = accG[r];
        acc10[8] = accH[0]; acc10[9] = accH[1];
        const float* wp[10];
#pragma unroll
        for (int r = 0; r < 8; ++r)
            wp[r] = Wih + (size_t)((r & 3) * HID + i0 + (r >> 2)) * ldWih + KX + ks;
        wp[8] = W1 + (size_t)i0 * (2 * HID) + HID + ks;
        wp[9] = W1 + (size_t)(i0 + 1) * (2 * HID) + HID + ks;
        gacc<64, 10, false>(acc10, cT + (size_t)ks * 64 + lane, wp);
#pragma unroll
        for (int r = 0; r < 8; ++r) accG[r] = acc10[r];
        accH[0] = acc10[8]; accH[1] = acc10[9];
    }
    {   // recurrent h part
        const int ks = wv * 64;
        const float* wp[8];
#pragma unroll
        for (int r = 0; r < 8; ++r)
            wp[r] = Whh + (size_t)((r & 3) * HID + i0 + (r >> 2)) * HID + ks;
        gacc<64, 8, false>(accG, hT + (size_t)ks * 64 + lane, wp);
    }
    __syncthreads();
#pragma unroll
    for (int r = 0; r < 8; ++r) sm.cell.red[wv][r][lane] = accG[r];
    if constexpr (FUSE) {
        sm.cell.red[wv][8][lane] = accH[0];
        sm.cell.red[wv][9][lane] = accH[1];
    }
    __syncthreads();
    if (t < 128) {
        const int b = t & 63, hl = t >> 6;
        float gs[4];
#pragma unroll
        for (int g = 0; g < 4; ++g) {
            const int row = g * HID + i0 + hl;
            float s = bih[row] + bhh[row];
#pragma unroll
            for (int w = 0; w < 8; ++w) s += sm.cell.red[w][hl * 4 + g][b];
            gs[g] = s;
        }
        const float ig = 1.f / (1.f + __expf(-gs[0]));
        const float fg = 1.f / (1.f + __expf(-gs[1]));
        const float gg = tanhf(gs[2]);
        const float og = 1.f / (1.f + __expf(-gs[3]));
        const float c2 = fg * cLds[hl * 64 + b] + ig * gg;
        cLds[hl * 64 + b] = c2;
        stv(hTout + (size_t)(i0 + hl) * 64 + b, og * tanhf(c2));
    } else if (FUSE && t < 256) {
        const int b = t & 63, hl = (t >> 6) - 2;
        float s = hpartLds[hl * 64 + b];
#pragma unroll
        for (int w = 0; w < 8; ++w) s += sm.cell.red[w][8 + hl][b];
        stv(hidB + (size_t)b * HID + i0 + hl, fmaxf(s, 0.f));
    }
}

// dual GEMV: ub = Pm@prev + p0 ; hpart(LDS) = W1a@prev + b1
__device__ __forceinline__ void phase_dual(SMem& sm, int i0,
    const float* __restrict__ prevT,
    const float* __restrict__ Pm, const float* __restrict__ p0v,
    const float* __restrict__ W1, const float* __restrict__ b1,
    float* ubB, float* hpartLds)
{
    const int t = threadIdx.x, wv = t >> 6, lane = t & 63;
    const int ks = wv * 64;
    float acc[4] = {};
    const float* wp[4];
    wp[0] = Pm + (size_t)i0 * HID + ks;
    wp[1] = Pm + (size_t)(i0 + 1) * HID + ks;
    wp[2] = W1 + (size_t)i0 * (2 * HID) + ks;
    wp[3] = W1 + (size_t)(i0 + 1) * (2 * HID) + ks;
    gacc<64, 4, false>(acc, prevT + (size_t)ks * 64 + lane, wp);
    __syncthreads();
#pragma unroll
    for (int r = 0; r < 4; ++r) sm.cell.red[wv][r][lane] = acc[r];
    __syncthreads();
    if (t < 256) {
        const int b = t & 63, r = t >> 6;
        float s = 0.f;
#pragma unroll
        for (int w = 0; w < 8; ++w) s += sm.cell.red[w][r][b];
        if (r < 2) stv(ubB + (size_t)b * HID + i0 + r, s + p0v[i0 + r]);
        else       hpartLds[(r - 2) * 64 + b] = s + b1[i0 + r - 2];
    }
}

// ctx = Whw@chat + Whb
__device__ __forceinline__ void phase_G(SMem& sm, int i0,
    const float* __restrict__ chatT, const float* __restrict__ Whw,
    const float* __restrict__ Whb, float* ctxT)
{
    const int t = threadIdx.x, wv = t >> 6, lane = t & 63;
    const int ks = wv * 64;
    float acc[2] = {};
    const float* wp[2];
    wp[0] = Whw + (size_t)i0 * HID + ks;
    wp[1] = Whw + (size_t)(i0 + 1) * HID + ks;
    gacc<64, 2, false>(acc, chatT + (size_t)ks * 64 + lane, wp);
    __syncthreads();
    sm.cell.red[wv][0][lane] = acc[0];
    sm.cell.red[wv][1][lane] = acc[1];
    __syncthreads();
    if (t < 128) {
        const int b = t & 63, r = t >> 6;
        float s = Whb[i0 + r];
#pragma unroll
        for (int w = 0; w < 8; ++w) s += sm.cell.red[w][r][b];
        stv(ctxT + (size_t)(i0 + r) * 64 + b, s);
    }
}

// tail-only H: hid = relu(hpart + W1b@ctx)
__device__ __forceinline__ void phase_Htail(SMem& sm, int i0,
    const float* __restrict__ ctxT, const float* __restrict__ W1,
    const float* hpartLds, float* hidB)
{
    const int t = threadIdx.x, wv = t >> 6, lane = t & 63;
    const int ks = wv * 64;
    float acc[2] = {};
    const float* wp[2];
    wp[0] = W1 + (size_t)i0 * (2 * HID) + HID + ks;
    wp[1] = W1 + (size_t)(i0 + 1) * (2 * HID) + HID + ks;
    gacc<64, 2, false>(acc, ctxT + (size_t)ks * 64 + lane, wp);
    __syncthreads();
    sm.cell.red[wv][0][lane] = acc[0];
    sm.cell.red[wv][1][lane] = acc[1];
    __syncthreads();
    if (t < 128) {
        const int b = t & 63, r = t >> 6;
        float s = hpartLds[r * 64 + b];
#pragma unroll
        for (int w = 0; w < 8; ++w) s += sm.cell.red[w][r][b];
        stv(hidB + (size_t)b * HID + i0 + r, fmaxf(s, 0.f));
    }
}

// combine chunk partials -> chatT
__device__ __forceinline__ void phase_F(int bid,
    const float* pm, const float* ps, const float* pvB, float* chatT)
{
    const int t = threadIdx.x;
    if (t < 128) {
        const int b = t & 63, jj = t >> 6;
        const int j = bid * 2 + jj;
        float m[4], sd[4], pvv[4];
#pragma unroll
        for (int ch = 0; ch < 4; ++ch) m[ch]   = ldv(pm + b * 4 + ch);
#pragma unroll
        for (int ch = 0; ch < 4; ++ch) sd[ch]  = ldv(ps + b * 4 + ch);
#pragma unroll
        for (int ch = 0; ch < 4; ++ch) pvv[ch] = ldv(pvB + (size_t)(b * 4 + ch) * HID + j);
        float M = fmaxf(fmaxf(m[0], m[1]), fmaxf(m[2], m[3]));
        float den = 0.f, num = 0.f;
#pragma unroll
        for (int ch = 0; ch < 4; ++ch) {
            float e = __expf(m[ch] - M);
            den += e * sd[ch]; num += e * pvv[ch];
        }
        stv(chatT + (size_t)j * 64 + b, num / den);
    }
}

// logits for one step
__device__ __forceinline__ void phase_logits(SMem& sm, int bid,
    const float* __restrict__ hidB, const float* __restrict__ W2,
    const float* __restrict__ b2, float* __restrict__ out, int tstep)
{
    const int t  = threadIdx.x;
    const int b  = bid & 63;
    const int vg = bid >> 6;
    const int vp = t >> 5;
    const int kk = t & 31;
    float hreg[16];
    const float* hp = hidB + (size_t)b * HID + kk * 16;
#pragma unroll
    for (int k = 0; k < 16; ++k) hreg[k] = ldv(hp + k);
    const float* w = W2 + (size_t)(vg * 16 + vp) * HID + kk * 16;
    float s = 0.f;
#pragma unroll
    for (int k = 0; k < 16; ++k) s += hreg[k] * w[k];
    __syncthreads();
    sm.log.red[vp * 33 + kk] = s;
    __syncthreads();
    if (t < 16) {
        float acc = b2[vg * 16 + t];
#pragma unroll
        for (int k = 0; k < 32; ++k) acc += sm.log.red[t * 33 + k];
        out[((size_t)b * SLEN + tstep) * VOCAB + vg * 16 + t] = acc;
    }
}

// attention partials, f16 LDS-staged, non-temporal enc reads
__device__ __forceinline__ void phase_attn16(SMem& sm, int bid,
    const float* __restrict__ ubB, const __half* __restrict__ enc16,
    float* pm, float* ps, float* pvB)
{
    const int t    = threadIdx.x;
    const int b    = bid >> 2;
    const int ch   = bid & 3;
    const int half = t >> 8;
    const int col  = t & 255;
    const int le   = t & 31;
    const int seg  = t >> 5;
    const int sq   = t & 15;
    const int sl   = (t >> 4) & 31;

    sm.attn.u_s[t] = ldv(ubB + (size_t)b * HID + t);
    if (t == 0) { sm.attn.msh[0] = -3.0e38f; sm.attn.msh[1] = 0.f; sm.attn.msh[2] = 0.f; }
    float vx = 0.f, vy = 0.f;

    const uu4* src = reinterpret_cast<const uu4*>(enc16 + ((size_t)b * LLEN + ch * 256) * HID);
    uu4 R[4];
#pragma unroll
    for (int p = 0; p < 4; ++p)
        R[p] = __builtin_nontemporal_load(src + (size_t)sl * 64 + p * 16 + sq);
    __syncthreads();

    for (int blk = 0; blk < 8; ++blk) {
        {
            unsigned* dst = &sm.attn.enc[sl * 261];
#pragma unroll
            for (int p = 0; p < 4; ++p) {
                const int c4 = (p * 16 + sq) * 4;
                dst[c4] = R[p].x; dst[c4+1] = R[p].y; dst[c4+2] = R[p].z; dst[c4+3] = R[p].w;
            }
        }
        __syncthreads();
        if (blk < 7) {
#pragma unroll
            for (int p = 0; p < 4; ++p)
                R[p] = __builtin_nontemporal_load(src + ((size_t)(blk + 1) * 32 + sl) * 64 + p * 16 + sq);
        }
        {   // scores
            float eacc = 0.f;
            const unsigned* er = &sm.attn.enc[le * 261];
            const float* us = sm.attn.u_s;
#pragma unroll
            for (int uu = 0; uu < 16; ++uu) {
                const int u = seg * 16 + uu;
                float2 f2 = __half22float2(*reinterpret_cast<const __half2*>(&er[u]));
                eacc += us[2 * u] * f2.x + us[2 * u + 1] * f2.y;
            }
            sm.attn.accs[seg][le] = eacc;
        }
        __syncthreads();
        if (t < 32) {
            float e = 0.f;
#pragma unroll
            for (int s2 = 0; s2 < 16; ++s2) e += sm.attn.accs[s2][t];
            float bm = e;
#pragma unroll
            for (int off = 16; off > 0; off >>= 1) bm = fmaxf(bm, __shfl_xor(bm, off));
            const float m_old = sm.attn.msh[0];
            const float m_new = fmaxf(m_old, bm);
            const float wl = __expf(e - m_new);
            float sw = wl;
#pragma unroll
            for (int off = 16; off > 0; off >>= 1) sw += __shfl_xor(sw, off);
            sm.attn.w_s[t] = wl;
            if (t == 0) {
                const float sc = __expf(m_old - m_new);
                sm.attn.msh[2] = sc;
                sm.attn.msh[1] = sm.attn.msh[1] * sc + sw;
                sm.attn.msh[0] = m_new;
            }
        }
        __syncthreads();
        {
            const float sc = sm.attn.msh[2];
            vx *= sc; vy *= sc;
#pragma unroll
            for (int ll = 0; ll < 16; ++ll) {
                const int l = half * 16 + ll;
                const float wl = sm.attn.w_s[l];
                float2 f2 = __half22float2(*reinterpret_cast<const __half2*>(&sm.attn.enc[l * 261 + col]));
                vx += wl * f2.x; vy += wl * f2.y;
            }
        }
        __syncthreads();
    }
    if (half == 1) { sm.attn.u_s[2 * col] = vx; sm.attn.u_s[2 * col + 1] = vy; }
    __syncthreads();
    if (half == 0) {
        vx += sm.attn.u_s[2 * col];
        vy += sm.attn.u_s[2 * col + 1];
        const int pc = b * NCH + ch;
        stv(pvB + (size_t)pc * HID + 2 * col,     vx);
        stv(pvB + (size_t)pc * HID + 2 * col + 1, vy);
        if (t == 0) { stv(pm + pc, sm.attn.msh[0]); stv(ps + pc, sm.attn.msh[1]); }
    }
}

// f32 fallback
__device__ __forceinline__ void phase_attn32(SMem& sm, int bid,
    const float* __restrict__ ubB, const float* __restrict__ encf,
    float* pm, float* ps, float* pvB)
{
    const int t    = threadIdx.x;
    const int b    = bid >> 2;
    const int ch   = bid & 3;
    const int half = t >> 8;
    const int col  = t & 255;
    const int le   = t & 31;
    const int seg  = t >> 5;
    sm.attn.u_s[t] = ldv(ubB + (size_t)b * HID + t);
    if (t == 0) { sm.attn.msh[0] = -3.0e38f; sm.attn.msh[1] = 0.f; sm.attn.msh[2] = 0.f; }
    float vx = 0.f, vy = 0.f;
    __syncthreads();
    for (int blk = 0; blk < 8; ++blk) {
        const int l0 = ch * 256 + blk * 32;
        {
            const float* er = encf + ((size_t)b * LLEN + l0 + le) * HID + seg * 32;
            const float* us = sm.attn.u_s + seg * 32;
            float eacc = 0.f;
#pragma unroll
            for (int k = 0; k < 32; ++k) eacc += er[k] * us[k];
            sm.attn.accs[seg][le] = eacc;
        }
        __syncthreads();
        if (t < 32) {
            float e = 0.f;
#pragma unroll
            for (int s2 = 0; s2 < 16; ++s2) e += sm.attn.accs[s2][t];
            float bm = e;
#pragma unroll
            for (int off = 16; off > 0; off >>= 1) bm = fmaxf(bm, __shfl_xor(bm, off));
            const float m_old = sm.attn.msh[0];
            const float m_new = fmaxf(m_old, bm);
            const float wl = __expf(e - m_new);
            float sw = wl;
#pragma unroll
            for (int off = 16; off > 0; off >>= 1) sw += __shfl_xor(sw, off);
            sm.attn.w_s[t] = wl;
            if (t == 0) {
                const float sc = __expf(m_old - m_new);
                sm.attn.msh[2] = sc;
                sm.attn.msh[1] = sm.attn.msh[1] * sc + sw;
                sm.attn.msh[0] = m_new;
            }
        }
        __syncthreads();
        {
            const float sc = sm.attn.msh[2];
            vx *= sc; vy *= sc;
#pragma unroll
            for (int ll = 0; ll < 16; ++ll) {
                const int l = half * 16 + ll;
                const float wl = sm.attn.w_s[l];
                float2 f2 = *reinterpret_cast<const float2*>(encf + ((size_t)b * LLEN + l0 + l) * HID + 2 * col);
                vx += wl * f2.x; vy += wl * f2.y;
            }
        }
        __syncthreads();
    }
    if (half == 1) { sm.attn.u_s[2 * col] = vx; sm.attn.u_s[2 * col + 1] = vy; }
    __syncthreads();
    if (half == 0) {
        vx += sm.attn.u_s[2 * col];
        vy += sm.attn.u_s[2 * col + 1];
        const int pc = b * NCH + ch;
        stv(pvB + (size_t)pc * HID + 2 * col,     vx);
        stv(pvB + (size_t)pc * HID + 2 * col + 1, vy);
        if (t == 0) { stv(pm + pc, sm.attn.msh[0]); stv(ps + pc, sm.attn.msh[1]); }
    }
}

// ---------------------------------------------------------------------------
template<int USE16>
__global__ __launch_bounds__(NT, 2)
void k_seq(const float* __restrict__ xembT, const __half* __restrict__ enc16,
           const float* __restrict__ encf,
           const float* __restrict__ aWih, const float* __restrict__ aWhh,
           const float* __restrict__ abih, const float* __restrict__ abhh,
           const float* __restrict__ rWih, const float* __restrict__ rWhh,
           const float* __restrict__ rbih, const float* __restrict__ rbhh,
           const float* __restrict__ Pm, const float* __restrict__ p0v,
           const float* __restrict__ Whw, const float* __restrict__ Whb,
           const float* __restrict__ W1, const float* __restrict__ b1,
           const float* __restrict__ W2, const float* __restrict__ b2,
           float* h0T, float* hsT, float* ctxT,
           float* ubB, float* chatT, float* hidB,
           float* pvB, float* pm, float* ps,
           float* out, unsigned* bar)
{
    __shared__ SMem sm;
    __shared__ float cLds[3][128];      // block-private LSTM c-state
    __shared__ float hpartLds[128];     // block-private W1a@prev + b1
    const int bid = blockIdx.x;
    const int i0  = bid * 2;
    const int t0  = threadIdx.x;
    if (t0 < 128) { cLds[0][t0] = 0.f; cLds[1][t0] = 0.f; cLds[2][t0] = 0.f; hpartLds[t0] = 0.f; }
    __syncthreads();

    unsigned nb = 0;
    for (int t = 0; t < SLEN; ++t) {
        const int par = t & 1;
        const float* h0r  = h0T + (size_t)par * 32768;
        float*       h0w  = h0T + (size_t)(par ^ 1) * 32768;
        const float* hs0r = hsT + (size_t)(par * 2 + 0) * 32768;
        const float* hs1r = hsT + (size_t)(par * 2 + 1) * 32768;
        float*       hs0w = hsT + (size_t)((par ^ 1) * 2 + 0) * 32768;
        float*       hs1w = hsT + (size_t)((par ^ 1) * 2 + 1) * 32768;

        // A: att-cell (+ fused H(t-1) sharing the ctx scan)
        phase_cell<EMB, true, true, true>(sm, i0,
            xembT + (size_t)t * EMB * 64, ctxT, h0r,
            aWih, EMB + HID, aWhh, W1, abih, abhh,
            cLds[0], h0w, hpartLds, hidB);
        gridbar(bar, ++nb);
        // B: rnn layer 0
        phase_cell<HID, false, false, false>(sm, i0,
            h0w, nullptr, hs0r, rWih, HID, rWhh, nullptr, rbih, rbhh,
            cLds[1], hs0w, nullptr, nullptr);
        gridbar(bar, ++nb);
        // C: rnn layer 1
        phase_cell<HID, false, false, false>(sm, i0,
            hs0w, nullptr, hs1r,
            rWih + (size_t)G4 * HID, HID, rWhh + (size_t)G4 * HID, nullptr,
            rbih + G4, rbhh + G4, cLds[2], hs1w, nullptr, nullptr);
        gridbar(bar, ++nb);
        // D: logits(t-1) + dual GEMV (u -> ubB, hpart -> LDS)
        if (t > 0) phase_logits(sm, bid, hidB, W2, b2, out, t - 1);
        phase_dual(sm, i0, hs1w, Pm, p0v, W1, b1, ubB, hpartLds);
        gridbar(bar, ++nb);
        // E: attention partials
        if constexpr (USE16) phase_attn16(sm, bid, ubB, enc16, pm, ps, pvB);
        else                 phase_attn32(sm, bid, ubB, encf, pm, ps, pvB);
        gridbar(bar, ++nb);
        // F: combine -> chatT
        phase_F(bid, pm, ps, pvB, chatT);
        gridbar(bar, ++nb);
        // G: ctx = Whw@chat + Whb
        phase_G(sm, i0, chatT, Whw, Whb, ctxT);
        gridbar(bar, ++nb);
    }
    phase_Htail(sm, i0, ctxT, W1, hpartLds, hidB);
    gridbar(bar, ++nb);
    phase_logits(sm, bid, hidB, W2, b2, out, SLEN - 1);
}

// ---------------------------------------------------------------------------
extern "C" void kernel_launch(void* const* d_in, const int* in_sizes, int n_in,
                              void* d_out, int out_size, void* d_ws, size_t ws_size,
                              hipStream_t stream)
{
    const int*   y    = (const int*)  d_in[0];
    const float* enc  = (const float*)d_in[1];
    const float* emb  = (const float*)d_in[2];
    const float* aWih = (const float*)d_in[3];
    const float* aWhh = (const float*)d_in[4];
    const float* abih = (const float*)d_in[5];
    const float* abhh = (const float*)d_in[6];
    const float* rWih = (const float*)d_in[7];
    const float* rWhh = (const float*)d_in[8];
    const float* rbih = (const float*)d_in[9];
    const float* rbhh = (const float*)d_in[10];
    const float* Wsw  = (const float*)d_in[11];
    const float* Wsb  = (const float*)d_in[12];
    const float* Whw  = (const float*)d_in[13];
    const float* Whb  = (const float*)d_in[14];
    const float* W1   = (const float*)d_in[15];
    const float* b1   = (const float*)d_in[16];
    const float* W2   = (const float*)d_in[17];
    const float* b2   = (const float*)d_in[18];
    float* out = (float*)d_out;

    unsigned* bar = (unsigned*)d_ws;
    float* base  = (float*)((char*)d_ws + 1024);
    float* h0T   = base;                 // 2 x [512][64]
    float* hsT   = h0T + 2 * 32768;      // [par][layer][512][64]
    float* ctxT  = hsT + 4 * 32768;      // [512][64]
    float* zEnd  = ctxT + 32768;
    float* ubB   = zEnd;                 // [64][512]
    float* chatT = ubB + 32768;          // [512][64]
    float* hidB  = chatT + 32768;        // [64][512]
    float* pvB   = hidB + 32768;         // [256][512]
    float* pmb   = pvB + 131072;         // 256
    float* psb   = pmb + 256;            // 256
    float* Pm    = psb + 256;            // 512x512
    float* p0v   = Pm + 262144;          // 512
    float* xembT = p0v + 512;            // [128][256][64]
    __half* enc16 = (__half*)(xembT + 2097152);
    size_t need = (size_t)((char*)(xembT + 2097152) - (char*)d_ws)
                + sizeof(__half) * (size_t)BS * LLEN * HID;
    const bool use16 = (ws_size >= need);

    hipMemsetAsync(bar, 0, 64, stream);
    hipMemsetAsync(h0T, 0, (size_t)(zEnd - h0T) * sizeof(float), stream);

    k_embed<<<(SLEN * BS * EMB) / 256, 256, 0, stream>>>(y, emb, xembT);
    if (use16) k_cast<<<4096, 256, 0, stream>>>(enc, enc16, (BS * LLEN * HID) / 4);
    k_pmat<<<HID, 256, 0, stream>>>(Whw, Wsw, Wsb, Pm, p0v);

    if (use16)
        k_seq<1><<<NB, NT, 0, stream>>>(xembT, enc16, nullptr,
            aWih, aWhh, abih, abhh, rWih, rWhh, rbih, rbhh,
            Pm, p0v, Whw, Whb, W1, b1, W2, b2,
            h0T, hsT, ctxT, ubB, chatT, hidB, pvB, pmb, psb, out, bar);
    else
        k_seq<0><<<NB, NT, 0, stream>>>(xembT, nullptr, enc,
            aWih, aWhh, abih, abhh, rWih, rWhh, rbih, rbhh,
            Pm, p0v, Whw, Whb, W1, b1, W2, b2,
            h0T, hsT, ctxT, ubB, chatT, hidB, pvB, pmb, psb, out, bar);
}

// Round 5
// 24159.085 us; speedup vs baseline: 3.5373x; 3.5373x over previous
//
#include <hip/hip_runtime.h>
#include <hip/hip_fp16.h>

#define HID   512
#define EMB   256
#define VOCAB 64
#define NL    2
#define BS    64
#define SLEN  128
#define LLEN  1024
#define G4    2048
#define NCH   4
#define NB    256
#define NT    512
#define LDA   129   // LDS stride for staged activation tiles (conflict-free)

typedef float f32x4 __attribute__((ext_vector_type(4)));

// ---------------------------------------------------------------------------
// volatile (cache-bypassing, MALL-coherent) plain vector/scalar access.
// Plain VMEM ops -> full coalescing; volatile -> sc0 sc1 on gfx95x.
__device__ __forceinline__ f32x4 vld4(const float* p) {
    return *reinterpret_cast<const volatile f32x4*>(p);
}
__device__ __forceinline__ float vld1(const float* p) {
    return *reinterpret_cast<const volatile float*>(p);
}
__device__ __forceinline__ void vst1(float* p, float v) {
    *reinterpret_cast<volatile float*>(p) = v;
}

// ---------------------------------------------------------------------------
struct SCell { float As[64 * LDA]; float red[8][10][66]; };
struct SAttn { float u_s[512]; float w_s[32]; float msh[4]; float accs[16][34];
               unsigned enc[32 * 261]; };
struct SLog  { float red[16 * 33]; };
union SMem { SCell cell; SAttn attn; SLog log; };

// ---------------------------------------------------------------------------
// 2-level ALL-RELAXED grid barrier. No acquire/release fences (no L2 wb/inv).
// Visibility: volatile write-through stores drain (vmcnt 0) at each wave's
// s_barrier before lane 0 signals arrival; data is then MALL-resident.
__device__ __forceinline__ void gridbar(unsigned* bar, unsigned nb)
{
    __syncthreads();
    if (threadIdx.x == 0) {
        unsigned* grp = bar + (blockIdx.x & 7) * 32;   // 128 B apart
        unsigned old = __hip_atomic_fetch_add(grp, 1u, __ATOMIC_RELAXED,
                                              __HIP_MEMORY_SCOPE_AGENT);
        if (old == nb * 32u - 1u)                      // last of this group's 32
            __hip_atomic_fetch_add(bar + 512, 1u, __ATOMIC_RELAXED,
                                   __HIP_MEMORY_SCOPE_AGENT);
        while (__hip_atomic_load(bar + 512, __ATOMIC_RELAXED,
                                 __HIP_MEMORY_SCOPE_AGENT) < nb * 8u)
            __builtin_amdgcn_s_sleep(2);
    }
    __syncthreads();
}

// ---------------------------------------------------------------------------
// one-time kernels
__global__ __launch_bounds__(256)
void k_embed(const int* __restrict__ y, const float* __restrict__ emb,
             float* __restrict__ xemb)      // [t][b][256]
{
    int i = blockIdx.x * 256 + threadIdx.x;
    int ts = i >> 14;
    int r  = i & 16383;
    int b  = r >> 8;
    int e  = r & 255;
    xemb[i] = emb[y[b * SLEN + ts] * EMB + e];
}

__global__ __launch_bounds__(256)
void k_cast(const float* __restrict__ src, __half* __restrict__ dst, int n4)
{
    int i = blockIdx.x * 256 + threadIdx.x;
    int stride = gridDim.x * 256;
    for (; i < n4; i += stride) {
        float4 v = reinterpret_cast<const float4*>(src)[i];
        reinterpret_cast<__half2*>(dst)[2 * i]     = __floats2half2_rn(v.x, v.y);
        reinterpret_cast<__half2*>(dst)[2 * i + 1] = __floats2half2_rn(v.z, v.w);
    }
}

__global__ __launch_bounds__(256)
void k_pmat(const float* __restrict__ Whw, const float* __restrict__ Wsw,
            const float* __restrict__ Wsb, float* __restrict__ P,
            float* __restrict__ p0)
{
    const int i = blockIdx.x;
    const int t = threadIdx.x;
    float a0 = 0.f, a1 = 0.f, ap = 0.f;
    for (int h = 0; h < HID; ++h) {
        float whi = Whw[h * HID + i];
        a0 += whi * Wsw[h * HID + t];
        a1 += whi * Wsw[h * HID + t + 256];
        ap += whi * Wsb[h];
    }
    P[i * HID + t]       = a0;
    P[i * HID + t + 256] = a1;
    if (t == 0) p0[i] = ap;
}

// ---------------------------------------------------------------------------
// stage one [64][128] f32 tile of activations into LDS (volatile reads)
__device__ __forceinline__ void stageV(SMem& sm, const float* A, int K, int k0)
{
    const int t = threadIdx.x;
#pragma unroll
    for (int p = 0; p < 4; ++p) {
        int f = p * 512 + t;
        int b = f >> 5;
        int q = f & 31;
        f32x4 d = vld4(A + (size_t)b * K + k0 + q * 4);
        float* dst = &sm.cell.As[b * LDA + q * 4];
        dst[0] = d.x; dst[1] = d.y; dst[2] = d.z; dst[3] = d.w;
    }
}

// ---------------------------------------------------------------------------
// fused LSTM cell, 2 h-rows (8 gate rows) per block; optional fused hid(t-1)
// rows sharing the ctx scan (FUSE).
template<bool HASC, bool FUSE>
__device__ __forceinline__ void phase_cell(SMem& sm, int i0, int KX,
    const float* __restrict__ xA, const float* ctxA, const float* hA,
    const float* __restrict__ Wih, int ldWih,
    const float* __restrict__ Whh, const float* __restrict__ W1row,
    const float* __restrict__ bih, const float* __restrict__ bhh,
    float* cPriv, const float* hpartPriv,
    float* h_out, float* hidB)
{
    const int t    = threadIdx.x;
    const int wv   = __builtin_amdgcn_readfirstlane(t >> 6);
    const int lane = t & 63;
    const int kw   = wv * 16;
    float acc[8] = {};
    float accH0 = 0.f, accH1 = 0.f;

    for (int seg = 0; seg < 3; ++seg) {
        const float* A; int K; const float* W; int ldW; int co;
        if (seg == 0)      { A = xA;   K = KX;  W = Wih; ldW = ldWih; co = 0;  }
        else if (seg == 1) { if (!HASC) continue;
                             A = ctxA; K = HID; W = Wih; ldW = ldWih; co = KX; }
        else               { A = hA;   K = HID; W = Whh; ldW = HID;   co = 0;  }
        for (int k0 = 0; k0 < K; k0 += 128) {
            __syncthreads();
            stageV(sm, A, K, k0);
            __syncthreads();
#pragma unroll
            for (int kk = 0; kk < 16; ++kk) {
                const float a = sm.cell.As[lane * LDA + kw + kk];
                const int k = co + k0 + kw + kk;
#pragma unroll
                for (int r = 0; r < 8; ++r)
                    acc[r] += a * W[(size_t)((r >> 1) * HID + i0 + (r & 1)) * ldW + k];
                if (FUSE && seg == 1) {
                    const int kc = k0 + kw + kk;
                    accH0 += a * W1row[kc];
                    accH1 += a * W1row[2 * HID + kc];
                }
            }
        }
    }
    __syncthreads();
#pragma unroll
    for (int r = 0; r < 8; ++r) sm.cell.red[wv][r][lane] = acc[r];
    if (FUSE) { sm.cell.red[wv][8][lane] = accH0; sm.cell.red[wv][9][lane] = accH1; }
    __syncthreads();
    if (t < 128) {
        const int b = t & 63, hl = t >> 6;
        float gs[4];
#pragma unroll
        for (int g = 0; g < 4; ++g) {
            const int row = g * HID + i0 + hl;
            float s = bih[row] + bhh[row];
#pragma unroll
            for (int w = 0; w < 8; ++w) s += sm.cell.red[w][g * 2 + hl][b];
            gs[g] = s;
        }
        const float ig = 1.f / (1.f + __expf(-gs[0]));
        const float fg = 1.f / (1.f + __expf(-gs[1]));
        const float gg = tanhf(gs[2]);
        const float og = 1.f / (1.f + __expf(-gs[3]));
        const float c2 = fg * cPriv[hl * 64 + b] + ig * gg;
        cPriv[hl * 64 + b] = c2;
        vst1(h_out + (size_t)b * HID + i0 + hl, og * tanhf(c2));
    } else if (FUSE && t < 256) {
        const int b = t & 63, hl = (t >> 6) - 2;
        float s = hpartPriv[hl * 64 + b];
#pragma unroll
        for (int w = 0; w < 8; ++w) s += sm.cell.red[w][8 + hl][b];
        vst1(hidB + (size_t)b * HID + i0 + hl, fmaxf(s, 0.f));
    }
}

// dual GEMV: ub = Pm@prev + p0 ; hpart(LDS) = W1a@prev + b1
__device__ __forceinline__ void phase_dual(SMem& sm, int i0,
    const float* prevA, const float* __restrict__ Pm,
    const float* __restrict__ p0v, const float* __restrict__ W1,
    const float* __restrict__ b1, float* ubB, float* hpartPriv)
{
    const int t    = threadIdx.x;
    const int wv   = __builtin_amdgcn_readfirstlane(t >> 6);
    const int lane = t & 63;
    const int kw   = wv * 16;
    float acc[4] = {};
    for (int k0 = 0; k0 < HID; k0 += 128) {
        __syncthreads();
        stageV(sm, prevA, HID, k0);
        __syncthreads();
#pragma unroll
        for (int kk = 0; kk < 16; ++kk) {
            const float a = sm.cell.As[lane * LDA + kw + kk];
            const int k = k0 + kw + kk;
            acc[0] += a * Pm[(size_t)i0 * HID + k];
            acc[1] += a * Pm[(size_t)(i0 + 1) * HID + k];
            acc[2] += a * W1[(size_t)i0 * 2 * HID + k];
            acc[3] += a * W1[(size_t)(i0 + 1) * 2 * HID + k];
        }
    }
    __syncthreads();
#pragma unroll
    for (int r = 0; r < 4; ++r) sm.cell.red[wv][r][lane] = acc[r];
    __syncthreads();
    if (t < 256) {
        const int b = t & 63, r = t >> 6;
        float s = 0.f;
#pragma unroll
        for (int w = 0; w < 8; ++w) s += sm.cell.red[w][r][b];
        if (r < 2) vst1(ubB + (size_t)b * HID + i0 + r, s + p0v[i0 + r]);
        else       hpartPriv[(r - 2) * 64 + b] = s + b1[i0 + r - 2];
    }
}

// generic 2-row GEMV over K=512: out = W@act (+bias) (+hpart, relu)
template<bool RELU>
__device__ __forceinline__ void phase_lin2(SMem& sm, int i0,
    const float* actA, const float* __restrict__ W, int ldW,
    const float* __restrict__ bias, const float* hpartPriv, float* outB)
{
    const int t    = threadIdx.x;
    const int wv   = __builtin_amdgcn_readfirstlane(t >> 6);
    const int lane = t & 63;
    const int kw   = wv * 16;
    float a0 = 0.f, a1 = 0.f;
    for (int k0 = 0; k0 < HID; k0 += 128) {
        __syncthreads();
        stageV(sm, actA, HID, k0);
        __syncthreads();
#pragma unroll
        for (int kk = 0; kk < 16; ++kk) {
            const float a = sm.cell.As[lane * LDA + kw + kk];
            const int k = k0 + kw + kk;
            a0 += a * W[(size_t)i0 * ldW + k];
            a1 += a * W[(size_t)(i0 + 1) * ldW + k];
        }
    }
    __syncthreads();
    sm.cell.red[wv][0][lane] = a0;
    sm.cell.red[wv][1][lane] = a1;
    __syncthreads();
    if (t < 128) {
        const int b = t & 63, r = t >> 6;
        float s = bias ? bias[i0 + r] : hpartPriv[r * 64 + b];
#pragma unroll
        for (int w = 0; w < 8; ++w) s += sm.cell.red[w][r][b];
        if (RELU) s = fmaxf(s, 0.f);
        vst1(outB + (size_t)b * HID + i0 + r, s);
    }
}

// combine chunk partials -> chat [b][512]
__device__ __forceinline__ void phase_F(int bid,
    const float* pm, const float* ps, const float* pvB, float* chatB)
{
    const int t = threadIdx.x;
    if (t < 128) {
        const int i = bid * 128 + t;
        const int b = i >> 9;
        const int j = i & 511;
        float m[4], sd[4], pvv[4];
#pragma unroll
        for (int c = 0; c < 4; ++c) m[c]   = vld1(pm + b * 4 + c);
#pragma unroll
        for (int c = 0; c < 4; ++c) sd[c]  = vld1(ps + b * 4 + c);
#pragma unroll
        for (int c = 0; c < 4; ++c) pvv[c] = vld1(pvB + (size_t)(b * 4 + c) * HID + j);
        float M = fmaxf(fmaxf(m[0], m[1]), fmaxf(m[2], m[3]));
        float den = 0.f, num = 0.f;
#pragma unroll
        for (int c = 0; c < 4; ++c) {
            float e = __expf(m[c] - M);
            den += e * sd[c]; num += e * pvv[c];
        }
        vst1(chatB + (size_t)b * HID + j, num / den);
    }
}

// logits for one step (block -> (b, v-group of 16))
__device__ __forceinline__ void phase_logits(SMem& sm, int bid,
    const float* hidB, const float* __restrict__ W2,
    const float* __restrict__ b2, float* __restrict__ out, int tstep)
{
    const int t  = threadIdx.x;
    const int b  = bid & 63;
    const int vg = bid >> 6;
    const int vp = t >> 5;
    const int kk = t & 31;
    f32x4 h0 = vld4(hidB + (size_t)b * HID + kk * 16);
    f32x4 h1 = vld4(hidB + (size_t)b * HID + kk * 16 + 4);
    f32x4 h2 = vld4(hidB + (size_t)b * HID + kk * 16 + 8);
    f32x4 h3 = vld4(hidB + (size_t)b * HID + kk * 16 + 12);
    const float* w = W2 + (size_t)(vg * 16 + vp) * HID + kk * 16;
    float s = h0.x*w[0] + h0.y*w[1] + h0.z*w[2] + h0.w*w[3]
            + h1.x*w[4] + h1.y*w[5] + h1.z*w[6] + h1.w*w[7]
            + h2.x*w[8] + h2.y*w[9] + h2.z*w[10] + h2.w*w[11]
            + h3.x*w[12] + h3.y*w[13] + h3.z*w[14] + h3.w*w[15];
    __syncthreads();
    sm.log.red[vp * 33 + kk] = s;
    __syncthreads();
    if (t < 16) {
        float acc = b2[vg * 16 + t];
#pragma unroll
        for (int k = 0; k < 32; ++k) acc += sm.log.red[t * 33 + k];
        out[((size_t)b * SLEN + tstep) * VOCAB + vg * 16 + t] = acc;
    }
}

// attention partials, f16 LDS-staged, CACHED enc reads, register prefetch
__device__ __forceinline__ void phase_attn16(SMem& sm, int bid,
    const float* ubB, const __half* __restrict__ enc16,
    float* pm, float* ps, float* pvB)
{
    const int t    = threadIdx.x;
    const int b    = bid >> 2;
    const int ch   = bid & 3;
    const int half = t >> 8;
    const int col  = t & 255;
    const int le   = t & 31;
    const int seg  = t >> 5;
    const int sq   = t & 15;
    const int sl   = (t >> 4) & 31;

    sm.attn.u_s[t] = vld1(ubB + (size_t)b * HID + t);
    if (t == 0) { sm.attn.msh[0] = -3.0e38f; sm.attn.msh[1] = 0.f; sm.attn.msh[2] = 0.f; }
    float vx = 0.f, vy = 0.f;

    const uint4* src = reinterpret_cast<const uint4*>(enc16 + ((size_t)b * LLEN + ch * 256) * HID);
    uint4 R[4];
#pragma unroll
    for (int p = 0; p < 4; ++p) R[p] = src[(size_t)sl * 64 + p * 16 + sq];
    __syncthreads();

    for (int blk = 0; blk < 8; ++blk) {
        {
            unsigned* dst = &sm.attn.enc[sl * 261];
#pragma unroll
            for (int p = 0; p < 4; ++p) {
                const int c4 = (p * 16 + sq) * 4;
                dst[c4] = R[p].x; dst[c4+1] = R[p].y; dst[c4+2] = R[p].z; dst[c4+3] = R[p].w;
            }
        }
        __syncthreads();
        if (blk < 7) {
#pragma unroll
            for (int p = 0; p < 4; ++p)
                R[p] = src[((size_t)(blk + 1) * 32 + sl) * 64 + p * 16 + sq];
        }
        {   // scores
            float eacc = 0.f;
            const unsigned* er = &sm.attn.enc[le * 261];
            const float* us = sm.attn.u_s;
#pragma unroll
            for (int uu = 0; uu < 16; ++uu) {
                const int u = seg * 16 + uu;
                float2 f2 = __half22float2(*reinterpret_cast<const __half2*>(&er[u]));
                eacc += us[2 * u] * f2.x + us[2 * u + 1] * f2.y;
            }
            sm.attn.accs[seg][le] = eacc;
        }
        __syncthreads();
        if (t < 32) {
            float e = 0.f;
#pragma unroll
            for (int s2 = 0; s2 < 16; ++s2) e += sm.attn.accs[s2][t];
            float bm = e;
#pragma unroll
            for (int off = 16; off > 0; off >>= 1) bm = fmaxf(bm, __shfl_xor(bm, off));
            const float m_old = sm.attn.msh[0];
            const float m_new = fmaxf(m_old, bm);
            const float wl = __expf(e - m_new);
            float sw = wl;
#pragma unroll
            for (int off = 16; off > 0; off >>= 1) sw += __shfl_xor(sw, off);
            sm.attn.w_s[t] = wl;
            if (t == 0) {
                const float sc = __expf(m_old - m_new);
                sm.attn.msh[2] = sc;
                sm.attn.msh[1] = sm.attn.msh[1] * sc + sw;
                sm.attn.msh[0] = m_new;
            }
        }
        __syncthreads();
        {
            const float sc = sm.attn.msh[2];
            vx *= sc; vy *= sc;
#pragma unroll
            for (int ll = 0; ll < 16; ++ll) {
                const int l = half * 16 + ll;
                const float wl = sm.attn.w_s[l];
                float2 f2 = __half22float2(*reinterpret_cast<const __half2*>(&sm.attn.enc[l * 261 + col]));
                vx += wl * f2.x; vy += wl * f2.y;
            }
        }
        __syncthreads();
    }
    if (half == 1) { sm.attn.u_s[2 * col] = vx; sm.attn.u_s[2 * col + 1] = vy; }
    __syncthreads();
    if (half == 0) {
        vx += sm.attn.u_s[2 * col];
        vy += sm.attn.u_s[2 * col + 1];
        const int pc = b * NCH + ch;
        vst1(pvB + (size_t)pc * HID + 2 * col,     vx);
        vst1(pvB + (size_t)pc * HID + 2 * col + 1, vy);
        if (t == 0) { vst1(pm + pc, sm.attn.msh[0]); vst1(ps + pc, sm.attn.msh[1]); }
    }
}

// f32 fallback (direct cached global enc reads)
__device__ __forceinline__ void phase_attn32(SMem& sm, int bid,
    const float* ubB, const float* __restrict__ encf,
    float* pm, float* ps, float* pvB)
{
    const int t    = threadIdx.x;
    const int b    = bid >> 2;
    const int ch   = bid & 3;
    const int half = t >> 8;
    const int col  = t & 255;
    const int le   = t & 31;
    const int seg  = t >> 5;
    sm.attn.u_s[t] = vld1(ubB + (size_t)b * HID + t);
    if (t == 0) { sm.attn.msh[0] = -3.0e38f; sm.attn.msh[1] = 0.f; sm.attn.msh[2] = 0.f; }
    float vx = 0.f, vy = 0.f;
    __syncthreads();
    for (int blk = 0; blk < 8; ++blk) {
        const int l0 = ch * 256 + blk * 32;
        {
            const float* er = encf + ((size_t)b * LLEN + l0 + le) * HID + seg * 32;
            const float* us = sm.attn.u_s + seg * 32;
            float eacc = 0.f;
#pragma unroll
            for (int k = 0; k < 32; ++k) eacc += er[k] * us[k];
            sm.attn.accs[seg][le] = eacc;
        }
        __syncthreads();
        if (t < 32) {
            float e = 0.f;
#pragma unroll
            for (int s2 = 0; s2 < 16; ++s2) e += sm.attn.accs[s2][t];
            float bm = e;
#pragma unroll
            for (int off = 16; off > 0; off >>= 1) bm = fmaxf(bm, __shfl_xor(bm, off));
            const float m_old = sm.attn.msh[0];
            const float m_new = fmaxf(m_old, bm);
            const float wl = __expf(e - m_new);
            float sw = wl;
#pragma unroll
            for (int off = 16; off > 0; off >>= 1) sw += __shfl_xor(sw, off);
            sm.attn.w_s[t] = wl;
            if (t == 0) {
                const float sc = __expf(m_old - m_new);
                sm.attn.msh[2] = sc;
                sm.attn.msh[1] = sm.attn.msh[1] * sc + sw;
                sm.attn.msh[0] = m_new;
            }
        }
        __syncthreads();
        {
            const float sc = sm.attn.msh[2];
            vx *= sc; vy *= sc;
#pragma unroll
            for (int ll = 0; ll < 16; ++ll) {
                const int l = half * 16 + ll;
                const float wl = sm.attn.w_s[l];
                float2 f2 = *reinterpret_cast<const float2*>(encf + ((size_t)b * LLEN + l0 + l) * HID + 2 * col);
                vx += wl * f2.x; vy += wl * f2.y;
            }
        }
        __syncthreads();
    }
    if (half == 1) { sm.attn.u_s[2 * col] = vx; sm.attn.u_s[2 * col + 1] = vy; }
    __syncthreads();
    if (half == 0) {
        vx += sm.attn.u_s[2 * col];
        vy += sm.attn.u_s[2 * col + 1];
        const int pc = b * NCH + ch;
        vst1(pvB + (size_t)pc * HID + 2 * col,     vx);
        vst1(pvB + (size_t)pc * HID + 2 * col + 1, vy);
        if (t == 0) { vst1(pm + pc, sm.attn.msh[0]); vst1(ps + pc, sm.attn.msh[1]); }
    }
}

// ---------------------------------------------------------------------------
template<int USE16>
__global__ __launch_bounds__(NT, 1)
void k_seq(const float* __restrict__ xemb, const __half* __restrict__ enc16,
           const float* __restrict__ encf,
           const float* __restrict__ aWih, const float* __restrict__ aWhh,
           const float* __restrict__ abih, const float* __restrict__ abhh,
           const float* __restrict__ rWih, const float* __restrict__ rWhh,
           const float* __restrict__ rbih, const float* __restrict__ rbhh,
           const float* __restrict__ Pm, const float* __restrict__ p0v,
           const float* __restrict__ Whw, const float* __restrict__ Whb,
           const float* __restrict__ W1, const float* __restrict__ b1,
           const float* __restrict__ W2, const float* __restrict__ b2,
           float* h0, float* hs, float* ctxb,
           float* ub, float* chat, float* hid,
           float* pvB, float* pm, float* ps,
           float* out, unsigned* bar)
{
    __shared__ SMem sm;
    __shared__ float cPriv[3][128];
    __shared__ float hpartPriv[128];
    const int bid = blockIdx.x;
    const int i0  = bid * 2;
    const int t0  = threadIdx.x;
    if (t0 < 128) { cPriv[0][t0] = 0.f; cPriv[1][t0] = 0.f; cPriv[2][t0] = 0.f;
                    hpartPriv[t0] = 0.f; }
    __syncthreads();

    const float* W1row = W1 + (size_t)i0 * (2 * HID) + HID;  // FUSE rows (ctx half)
    unsigned nb = 0;

    for (int t = 0; t < SLEN; ++t) {
        const int par = t & 1;
        const float* h0r  = h0 + (size_t)par * BS * HID;
        float*       h0w  = h0 + (size_t)(par ^ 1) * BS * HID;
        const float* hs0r = hs + (size_t)(par * 2 + 0) * BS * HID;
        const float* hs1r = hs + (size_t)(par * 2 + 1) * BS * HID;
        float*       hs0w = hs + (size_t)((par ^ 1) * 2 + 0) * BS * HID;
        float*       hs1w = hs + (size_t)((par ^ 1) * 2 + 1) * BS * HID;

        // A: att-cell (+ fused hid(t-1) sharing the ctx scan)
        phase_cell<true, true>(sm, i0, EMB,
            xemb + (size_t)t * BS * EMB, ctxb, h0r,
            aWih, EMB + HID, aWhh, W1row, abih, abhh,
            cPriv[0], hpartPriv, h0w, hid);
        gridbar(bar, ++nb);
        // B: rnn layer 0
        phase_cell<false, false>(sm, i0, HID,
            h0w, nullptr, hs0r, rWih, HID, rWhh, nullptr, rbih, rbhh,
            cPriv[1], nullptr, hs0w, nullptr);
        gridbar(bar, ++nb);
        // C: rnn layer 1
        phase_cell<false, false>(sm, i0, HID,
            hs0w, nullptr, hs1r,
            rWih + (size_t)G4 * HID, HID, rWhh + (size_t)G4 * HID, nullptr,
            rbih + G4, rbhh + G4, cPriv[2], nullptr, hs1w, nullptr);
        gridbar(bar, ++nb);
        // D: logits(t-1) + dual GEMV (u -> ub, hpart -> LDS)
        if (t > 0) phase_logits(sm, bid, hid, W2, b2, out, t - 1);
        phase_dual(sm, i0, hs1w, Pm, p0v, W1, b1, ub, hpartPriv);
        gridbar(bar, ++nb);
        // E: attention partials
        if constexpr (USE16) phase_attn16(sm, bid, ub, enc16, pm, ps, pvB);
        else                 phase_attn32(sm, bid, ub, encf, pm, ps, pvB);
        gridbar(bar, ++nb);
        // F: combine -> chat
        phase_F(bid, pm, ps, pvB, chat);
        gridbar(bar, ++nb);
        // G: ctx = Whw@chat + Whb
        phase_lin2<false>(sm, i0, chat, Whw, HID, Whb, nullptr, ctxb);
        gridbar(bar, ++nb);
    }
    // tail: hid(S-1) = relu(hpart + W1b@ctx), then logits(S-1)
    phase_lin2<true>(sm, i0, ctxb, W1 + HID, 2 * HID, nullptr, hpartPriv, hid);
    gridbar(bar, ++nb);
    phase_logits(sm, bid, hid, W2, b2, out, SLEN - 1);
}

// ---------------------------------------------------------------------------
extern "C" void kernel_launch(void* const* d_in, const int* in_sizes, int n_in,
                              void* d_out, int out_size, void* d_ws, size_t ws_size,
                              hipStream_t stream)
{
    const int*   y    = (const int*)  d_in[0];
    const float* enc  = (const float*)d_in[1];
    const float* emb  = (const float*)d_in[2];
    const float* aWih = (const float*)d_in[3];
    const float* aWhh = (const float*)d_in[4];
    const float* abih = (const float*)d_in[5];
    const float* abhh = (const float*)d_in[6];
    const float* rWih = (const float*)d_in[7];
    const float* rWhh = (const float*)d_in[8];
    const float* rbih = (const float*)d_in[9];
    const float* rbhh = (const float*)d_in[10];
    const float* Wsw  = (const float*)d_in[11];
    const float* Wsb  = (const float*)d_in[12];
    const float* Whw  = (const float*)d_in[13];
    const float* Whb  = (const float*)d_in[14];
    const float* W1   = (const float*)d_in[15];
    const float* b1   = (const float*)d_in[16];
    const float* W2   = (const float*)d_in[17];
    const float* b2   = (const float*)d_in[18];
    float* out = (float*)d_out;

    unsigned* bar = (unsigned*)d_ws;
    float* p = (float*)((char*)d_ws + 4096);
    // zero region: h0 (2), hs (4), ctxb (1)  -> 7 x [64][512]
    float* h0   = p;  p += 2 * BS * HID;
    float* hs   = p;  p += 4 * BS * HID;
    float* ctxb = p;  p += BS * HID;
    float* zEnd = p;
    float* ub   = p;  p += BS * HID;
    float* chat = p;  p += BS * HID;
    float* hid  = p;  p += BS * HID;
    float* pvB  = p;  p += (size_t)BS * NCH * HID;
    float* pmb  = p;  p += 256;
    float* psb  = p;  p += 256;
    float* Pm   = p;  p += HID * HID;
    float* p0v  = p;  p += HID;
    float* xemb = p;  p += (size_t)SLEN * BS * EMB;
    __half* enc16 = (__half*)p;
    size_t need = (size_t)((char*)p - (char*)d_ws)
                + sizeof(__half) * (size_t)BS * LLEN * HID;
    const bool use16 = (ws_size >= need);

    hipMemsetAsync(bar, 0, 4096, stream);
    hipMemsetAsync(h0, 0, (size_t)(zEnd - h0) * sizeof(float), stream);

    k_embed<<<(SLEN * BS * EMB) / 256, 256, 0, stream>>>(y, emb, xemb);
    if (use16) k_cast<<<4096, 256, 0, stream>>>(enc, enc16, (BS * LLEN * HID) / 4);
    k_pmat<<<HID, 256, 0, stream>>>(Whw, Wsw, Wsb, Pm, p0v);

    if (use16)
        k_seq<1><<<NB, NT, 0, stream>>>(xemb, enc16, nullptr,
            aWih, aWhh, abih, abhh, rWih, rWhh, rbih, rbhh,
            Pm, p0v, Whw, Whb, W1, b1, W2, b2,
            h0, hs, ctxb, ub, chat, hid, pvB, pmb, psb, out, bar);
    else
        k_seq<0><<<NB, NT, 0, stream>>>(xemb, nullptr, enc,
            aWih, aWhh, abih, abhh, rWih, rWhh, rbih, rbhh,
            Pm, p0v, Whw, Whb, W1, b1, W2, b2,
            h0, hs, ctxb, ub, chat, hid, pvB, pmb, psb, out, bar);
}

// Round 6
// 18526.770 us; speedup vs baseline: 4.6127x; 1.3040x over previous
//
#include <hip/hip_runtime.h>
#include <hip/hip_fp16.h>

#define HID   512
#define EMB   256
#define VOCAB 64
#define NL    2
#define BS    64
#define SLEN  128
#define LLEN  1024
#define G4    2048
#define NCH   4
#define NB    256
#define NT    512
#define LDA   129   // LDS stride for staged activation tiles (conflict-free)

typedef float f32x4 __attribute__((ext_vector_type(4)));

// ---------------------------------------------------------------------------
// volatile (cache-bypassing, MALL-coherent) plain vector/scalar access
__device__ __forceinline__ f32x4 vld4(const float* p) {
    return *reinterpret_cast<const volatile f32x4*>(p);
}
__device__ __forceinline__ float vld1(const float* p) {
    return *reinterpret_cast<const volatile float*>(p);
}
__device__ __forceinline__ void vst1(float* p, float v) {
    *reinterpret_cast<volatile float*>(p) = v;
}

// ---------------------------------------------------------------------------
struct SCell { float As[2 * 64 * LDA]; float red[8][10][66]; };
struct SAttn { float u_s[512]; float w_s[32]; float msh[4]; float accs[16][34];
               unsigned enc[32 * 261]; };
struct SLog  { float red[16 * 33]; };
union SMem { SCell cell; SAttn attn; SLog log; };

// ---------------------------------------------------------------------------
// grid barrier v3: leader/release topology, all-relaxed (no L2 wb/inv).
// arr[g] at bar+g*32 (128B apart), rel[g] at bar+256+g*32, top at bar+512.
// 32 blocks/group; only 8 leaders poll top; members poll their group release.
__device__ __forceinline__ void gridbar(unsigned* bar, unsigned nb)
{
    __syncthreads();
    if (threadIdx.x == 0) {
        const unsigned g = blockIdx.x >> 5;
        unsigned* arr = bar + g * 32;
        unsigned* rel = bar + 256 + g * 32;
        unsigned* top = bar + 512;
        unsigned old = __hip_atomic_fetch_add(arr, 1u, __ATOMIC_RELAXED,
                                              __HIP_MEMORY_SCOPE_AGENT);
        if (old == nb * 32u - 1u)
            __hip_atomic_fetch_add(top, 1u, __ATOMIC_RELAXED,
                                   __HIP_MEMORY_SCOPE_AGENT);
        if ((blockIdx.x & 31u) == 0u) {
            while (__hip_atomic_load(top, __ATOMIC_RELAXED,
                                     __HIP_MEMORY_SCOPE_AGENT) < nb * 8u)
                __builtin_amdgcn_s_sleep(2);
            __hip_atomic_store(rel, nb, __ATOMIC_RELAXED,
                               __HIP_MEMORY_SCOPE_AGENT);
        } else {
            while (__hip_atomic_load(rel, __ATOMIC_RELAXED,
                                     __HIP_MEMORY_SCOPE_AGENT) < nb)
                __builtin_amdgcn_s_sleep(4);
        }
    }
    __syncthreads();
}

// ---------------------------------------------------------------------------
// one-time kernels
__global__ __launch_bounds__(256)
void k_embed(const int* __restrict__ y, const float* __restrict__ emb,
             float* __restrict__ xemb)      // [t][b][256]
{
    int i = blockIdx.x * 256 + threadIdx.x;
    int ts = i >> 14;
    int r  = i & 16383;
    int b  = r >> 8;
    int e  = r & 255;
    xemb[i] = emb[y[b * SLEN + ts] * EMB + e];
}

__global__ __launch_bounds__(256)
void k_cast(const float* __restrict__ src, __half* __restrict__ dst, int n4)
{
    int i = blockIdx.x * 256 + threadIdx.x;
    int stride = gridDim.x * 256;
    for (; i < n4; i += stride) {
        float4 v = reinterpret_cast<const float4*>(src)[i];
        reinterpret_cast<__half2*>(dst)[2 * i]     = __floats2half2_rn(v.x, v.y);
        reinterpret_cast<__half2*>(dst)[2 * i + 1] = __floats2half2_rn(v.z, v.w);
    }
}

__global__ __launch_bounds__(256)
void k_pmat(const float* __restrict__ Whw, const float* __restrict__ Wsw,
            const float* __restrict__ Wsb, float* __restrict__ P,
            float* __restrict__ p0)
{
    const int i = blockIdx.x;
    const int t = threadIdx.x;
    float a0 = 0.f, a1 = 0.f, ap = 0.f;
    for (int h = 0; h < HID; ++h) {
        float whi = Whw[h * HID + i];
        a0 += whi * Wsw[h * HID + t];
        a1 += whi * Wsw[h * HID + t + 256];
        ap += whi * Wsb[h];
    }
    P[i * HID + t]       = a0;
    P[i * HID + t + 256] = a1;
    if (t == 0) p0[i] = ap;
}

// ---------------------------------------------------------------------------
// pipelined staging helpers: 128-col tile, reg prefetch + double LDS buffer
__device__ __forceinline__ void loadT(f32x4 (&R)[4], const float* A, int K, int k0)
{
    const int t = threadIdx.x;
#pragma unroll
    for (int p = 0; p < 4; ++p) {
        int f = p * 512 + t;
        int b = f >> 5, q = f & 31;
        R[p] = vld4(A + (size_t)b * K + k0 + q * 4);
    }
}
__device__ __forceinline__ void writeT(SMem& sm, int buf, const f32x4 (&R)[4])
{
    const int t = threadIdx.x;
    float* Bp = sm.cell.As + buf * (64 * LDA);
#pragma unroll
    for (int p = 0; p < 4; ++p) {
        int f = p * 512 + t;
        int b = f >> 5, q = f & 31;
        float* dst = Bp + b * LDA + q * 4;
        dst[0] = R[p].x; dst[1] = R[p].y; dst[2] = R[p].z; dst[3] = R[p].w;
    }
}

// scan one activation segment (NTT 128-col tiles) against NRR weight rows.
// One __syncthreads per tile; load latency hidden one tile deep.
template<int NTT, int NRR>
__device__ __forceinline__ void segScan(SMem& sm, const float* A, int K,
    const float* const* wrow, float* acc, int kw, int lane)
{
    f32x4 Ra[4], Rb[4];
    loadT(Ra, A, K, 0);
    __syncthreads();                       // buffer handoff from previous use
#pragma unroll
    for (int j = 0; j < NTT; ++j) {
        if ((j & 1) == 0) { writeT(sm, 0, Ra); if (j + 1 < NTT) loadT(Rb, A, K, (j + 1) * 128); }
        else              { writeT(sm, 1, Rb); if (j + 1 < NTT) loadT(Ra, A, K, (j + 1) * 128); }
        __syncthreads();
        const float* as = sm.cell.As + (j & 1) * (64 * LDA) + lane * LDA + kw;
#pragma unroll
        for (int kk = 0; kk < 16; ++kk) {
            const float a = as[kk];
            const int k = j * 128 + kw + kk;
#pragma unroll
            for (int r = 0; r < NRR; ++r)
                acc[r] += a * wrow[r][k];
        }
    }
}

// ---------------------------------------------------------------------------
// fused LSTM cell, 2 h-rows (8 gate rows) per block; optional fused hid(t-1)
// rows sharing the ctx segment (FUSE).
template<int KX, bool HASC, bool FUSE>
__device__ __forceinline__ void phase_cell(SMem& sm, int i0,
    const float* xA, const float* ctxA, const float* hA,
    const float* __restrict__ Wih, int ldWih,
    const float* __restrict__ Whh, const float* __restrict__ W1row,
    const float* __restrict__ bih, const float* __restrict__ bhh,
    float* cPriv, const float* hpartPriv,
    float* h_out, float* hidB)
{
    const int t    = threadIdx.x;
    const int wv   = __builtin_amdgcn_readfirstlane(t >> 6);
    const int lane = t & 63;
    const int kw   = wv * 16;
    float acc[FUSE ? 10 : 8] = {};

    {   // x segment
        const float* w8[8];
#pragma unroll
        for (int r = 0; r < 8; ++r)
            w8[r] = Wih + (size_t)((r >> 1) * HID + i0 + (r & 1)) * ldWih;
        segScan<KX / 128, 8>(sm, xA, KX, w8, acc, kw, lane);
    }
    if constexpr (HASC) {   // ctx segment (+ fused hid rows)
        if constexpr (FUSE) {
            const float* w10[10];
#pragma unroll
            for (int r = 0; r < 8; ++r)
                w10[r] = Wih + (size_t)((r >> 1) * HID + i0 + (r & 1)) * ldWih + KX;
            w10[8] = W1row;
            w10[9] = W1row + 2 * HID;
            segScan<4, 10>(sm, ctxA, HID, w10, acc, kw, lane);
        } else {
            const float* w8[8];
#pragma unroll
            for (int r = 0; r < 8; ++r)
                w8[r] = Wih + (size_t)((r >> 1) * HID + i0 + (r & 1)) * ldWih + KX;
            segScan<4, 8>(sm, ctxA, HID, w8, acc, kw, lane);
        }
    }
    {   // recurrent h segment
        const float* w8[8];
#pragma unroll
        for (int r = 0; r < 8; ++r)
            w8[r] = Whh + (size_t)((r >> 1) * HID + i0 + (r & 1)) * HID;
        segScan<4, 8>(sm, hA, HID, w8, acc, kw, lane);
    }
    __syncthreads();
#pragma unroll
    for (int r = 0; r < 8; ++r) sm.cell.red[wv][r][lane] = acc[r];
    if constexpr (FUSE) {
        sm.cell.red[wv][8][lane] = acc[8];
        sm.cell.red[wv][9][lane] = acc[9];
    }
    __syncthreads();
    if (t < 128) {
        const int b = t & 63, hl = t >> 6;
        float gs[4];
#pragma unroll
        for (int g = 0; g < 4; ++g) {
            const int row = g * HID + i0 + hl;
            float s = bih[row] + bhh[row];
#pragma unroll
            for (int w = 0; w < 8; ++w) s += sm.cell.red[w][g * 2 + hl][b];
            gs[g] = s;
        }
        const float ig = 1.f / (1.f + __expf(-gs[0]));
        const float fg = 1.f / (1.f + __expf(-gs[1]));
        const float gg = tanhf(gs[2]);
        const float og = 1.f / (1.f + __expf(-gs[3]));
        const float c2 = fg * cPriv[hl * 64 + b] + ig * gg;
        cPriv[hl * 64 + b] = c2;
        vst1(h_out + (size_t)b * HID + i0 + hl, og * tanhf(c2));
    } else if (FUSE && t < 256) {
        const int b = t & 63, hl = (t >> 6) - 2;
        float s = hpartPriv[hl * 64 + b];
#pragma unroll
        for (int w = 0; w < 8; ++w) s += sm.cell.red[w][8 + hl][b];
        vst1(hidB + (size_t)b * HID + i0 + hl, fmaxf(s, 0.f));
    }
}

// dual GEMV: ub = Pm@prev + p0 ; hpart(LDS) = W1a@prev + b1
__device__ __forceinline__ void phase_dual(SMem& sm, int i0,
    const float* prevA, const float* __restrict__ Pm,
    const float* __restrict__ p0v, const float* __restrict__ W1,
    const float* __restrict__ b1, float* ubB, float* hpartPriv)
{
    const int t    = threadIdx.x;
    const int wv   = __builtin_amdgcn_readfirstlane(t >> 6);
    const int lane = t & 63;
    const int kw   = wv * 16;
    float acc[4] = {};
    const float* w4[4];
    w4[0] = Pm + (size_t)i0 * HID;
    w4[1] = Pm + (size_t)(i0 + 1) * HID;
    w4[2] = W1 + (size_t)i0 * 2 * HID;
    w4[3] = W1 + (size_t)(i0 + 1) * 2 * HID;
    segScan<4, 4>(sm, prevA, HID, w4, acc, kw, lane);
    __syncthreads();
#pragma unroll
    for (int r = 0; r < 4; ++r) sm.cell.red[wv][r][lane] = acc[r];
    __syncthreads();
    if (t < 256) {
        const int b = t & 63, r = t >> 6;
        float s = 0.f;
#pragma unroll
        for (int w = 0; w < 8; ++w) s += sm.cell.red[w][r][b];
        if (r < 2) vst1(ubB + (size_t)b * HID + i0 + r, s + p0v[i0 + r]);
        else       hpartPriv[(r - 2) * 64 + b] = s + b1[i0 + r - 2];
    }
}

// generic 2-row GEMV over K=512: out = W@act (+bias) (+hpart, relu)
template<bool RELU>
__device__ __forceinline__ void phase_lin2(SMem& sm, int i0,
    const float* actA, const float* __restrict__ W, int ldW,
    const float* __restrict__ bias, const float* hpartPriv, float* outB)
{
    const int t    = threadIdx.x;
    const int wv   = __builtin_amdgcn_readfirstlane(t >> 6);
    const int lane = t & 63;
    const int kw   = wv * 16;
    float acc[2] = {};
    const float* w2[2];
    w2[0] = W + (size_t)i0 * ldW;
    w2[1] = W + (size_t)(i0 + 1) * ldW;
    segScan<4, 2>(sm, actA, HID, w2, acc, kw, lane);
    __syncthreads();
    sm.cell.red[wv][0][lane] = acc[0];
    sm.cell.red[wv][1][lane] = acc[1];
    __syncthreads();
    if (t < 128) {
        const int b = t & 63, r = t >> 6;
        float s = bias ? bias[i0 + r] : hpartPriv[r * 64 + b];
#pragma unroll
        for (int w = 0; w < 8; ++w) s += sm.cell.red[w][r][b];
        if (RELU) s = fmaxf(s, 0.f);
        vst1(outB + (size_t)b * HID + i0 + r, s);
    }
}

// combine chunk partials -> chat [b][512]
__device__ __forceinline__ void phase_F(int bid,
    const float* pm, const float* ps, const float* pvB, float* chatB)
{
    const int t = threadIdx.x;
    if (t < 128) {
        const int i = bid * 128 + t;
        const int b = i >> 9;
        const int j = i & 511;
        float m[4], sd[4], pvv[4];
#pragma unroll
        for (int c = 0; c < 4; ++c) m[c]   = vld1(pm + b * 4 + c);
#pragma unroll
        for (int c = 0; c < 4; ++c) sd[c]  = vld1(ps + b * 4 + c);
#pragma unroll
        for (int c = 0; c < 4; ++c) pvv[c] = vld1(pvB + (size_t)(b * 4 + c) * HID + j);
        float M = fmaxf(fmaxf(m[0], m[1]), fmaxf(m[2], m[3]));
        float den = 0.f, num = 0.f;
#pragma unroll
        for (int c = 0; c < 4; ++c) {
            float e = __expf(m[c] - M);
            den += e * sd[c]; num += e * pvv[c];
        }
        vst1(chatB + (size_t)b * HID + j, num / den);
    }
}

// logits for one step (block -> (b, v-group of 16))
__device__ __forceinline__ void phase_logits(SMem& sm, int bid,
    const float* hidB, const float* __restrict__ W2,
    const float* __restrict__ b2, float* __restrict__ out, int tstep)
{
    const int t  = threadIdx.x;
    const int b  = bid & 63;
    const int vg = bid >> 6;
    const int vp = t >> 5;
    const int kk = t & 31;
    f32x4 h0 = vld4(hidB + (size_t)b * HID + kk * 16);
    f32x4 h1 = vld4(hidB + (size_t)b * HID + kk * 16 + 4);
    f32x4 h2 = vld4(hidB + (size_t)b * HID + kk * 16 + 8);
    f32x4 h3 = vld4(hidB + (size_t)b * HID + kk * 16 + 12);
    const float* w = W2 + (size_t)(vg * 16 + vp) * HID + kk * 16;
    float s = h0.x*w[0] + h0.y*w[1] + h0.z*w[2] + h0.w*w[3]
            + h1.x*w[4] + h1.y*w[5] + h1.z*w[6] + h1.w*w[7]
            + h2.x*w[8] + h2.y*w[9] + h2.z*w[10] + h2.w*w[11]
            + h3.x*w[12] + h3.y*w[13] + h3.z*w[14] + h3.w*w[15];
    __syncthreads();
    sm.log.red[vp * 33 + kk] = s;
    __syncthreads();
    if (t < 16) {
        float acc = b2[vg * 16 + t];
#pragma unroll
        for (int k = 0; k < 32; ++k) acc += sm.log.red[t * 33 + k];
        out[((size_t)b * SLEN + tstep) * VOCAB + vg * 16 + t] = acc;
    }
}

// attention partials, f16 LDS-staged, cached enc reads, register prefetch
__device__ __forceinline__ void phase_attn16(SMem& sm, int bid,
    const float* ubB, const __half* __restrict__ enc16,
    float* pm, float* ps, float* pvB)
{
    const int t    = threadIdx.x;
    const int b    = bid >> 2;
    const int ch   = bid & 3;
    const int half = t >> 8;
    const int col  = t & 255;
    const int le   = t & 31;
    const int seg  = t >> 5;
    const int sq   = t & 15;
    const int sl   = (t >> 4) & 31;

    sm.attn.u_s[t] = vld1(ubB + (size_t)b * HID + t);
    if (t == 0) { sm.attn.msh[0] = -3.0e38f; sm.attn.msh[1] = 0.f; sm.attn.msh[2] = 0.f; }
    float vx = 0.f, vy = 0.f;

    const uint4* src = reinterpret_cast<const uint4*>(enc16 + ((size_t)b * LLEN + ch * 256) * HID);
    uint4 R[4];
#pragma unroll
    for (int p = 0; p < 4; ++p) R[p] = src[(size_t)sl * 64 + p * 16 + sq];
    __syncthreads();

    for (int blk = 0; blk < 8; ++blk) {
        {
            unsigned* dst = &sm.attn.enc[sl * 261];
#pragma unroll
            for (int p = 0; p < 4; ++p) {
                const int c4 = (p * 16 + sq) * 4;
                dst[c4] = R[p].x; dst[c4+1] = R[p].y; dst[c4+2] = R[p].z; dst[c4+3] = R[p].w;
            }
        }
        __syncthreads();
        if (blk < 7) {
#pragma unroll
            for (int p = 0; p < 4; ++p)
                R[p] = src[((size_t)(blk + 1) * 32 + sl) * 64 + p * 16 + sq];
        }
        {   // scores
            float eacc = 0.f;
            const unsigned* er = &sm.attn.enc[le * 261];
            const float* us = sm.attn.u_s;
#pragma unroll
            for (int uu = 0; uu < 16; ++uu) {
                const int u = seg * 16 + uu;
                float2 f2 = __half22float2(*reinterpret_cast<const __half2*>(&er[u]));
                eacc += us[2 * u] * f2.x + us[2 * u + 1] * f2.y;
            }
            sm.attn.accs[seg][le] = eacc;
        }
        __syncthreads();
        if (t < 32) {
            float e = 0.f;
#pragma unroll
            for (int s2 = 0; s2 < 16; ++s2) e += sm.attn.accs[s2][t];
            float bm = e;
#pragma unroll
            for (int off = 16; off > 0; off >>= 1) bm = fmaxf(bm, __shfl_xor(bm, off));
            const float m_old = sm.attn.msh[0];
            const float m_new = fmaxf(m_old, bm);
            const float wl = __expf(e - m_new);
            float sw = wl;
#pragma unroll
            for (int off = 16; off > 0; off >>= 1) sw += __shfl_xor(sw, off);
            sm.attn.w_s[t] = wl;
            if (t == 0) {
                const float sc = __expf(m_old - m_new);
                sm.attn.msh[2] = sc;
                sm.attn.msh[1] = sm.attn.msh[1] * sc + sw;
                sm.attn.msh[0] = m_new;
            }
        }
        __syncthreads();
        {
            const float sc = sm.attn.msh[2];
            vx *= sc; vy *= sc;
#pragma unroll
            for (int ll = 0; ll < 16; ++ll) {
                const int l = half * 16 + ll;
                const float wl = sm.attn.w_s[l];
                float2 f2 = __half22float2(*reinterpret_cast<const __half2*>(&sm.attn.enc[l * 261 + col]));
                vx += wl * f2.x; vy += wl * f2.y;
            }
        }
        __syncthreads();
    }
    if (half == 1) { sm.attn.u_s[2 * col] = vx; sm.attn.u_s[2 * col + 1] = vy; }
    __syncthreads();
    if (half == 0) {
        vx += sm.attn.u_s[2 * col];
        vy += sm.attn.u_s[2 * col + 1];
        const int pc = b * NCH + ch;
        vst1(pvB + (size_t)pc * HID + 2 * col,     vx);
        vst1(pvB + (size_t)pc * HID + 2 * col + 1, vy);
        if (t == 0) { vst1(pm + pc, sm.attn.msh[0]); vst1(ps + pc, sm.attn.msh[1]); }
    }
}

// f32 fallback (direct cached global enc reads)
__device__ __forceinline__ void phase_attn32(SMem& sm, int bid,
    const float* ubB, const float* __restrict__ encf,
    float* pm, float* ps, float* pvB)
{
    const int t    = threadIdx.x;
    const int b    = bid >> 2;
    const int ch   = bid & 3;
    const int half = t >> 8;
    const int col  = t & 255;
    const int le   = t & 31;
    const int seg  = t >> 5;
    sm.attn.u_s[t] = vld1(ubB + (size_t)b * HID + t);
    if (t == 0) { sm.attn.msh[0] = -3.0e38f; sm.attn.msh[1] = 0.f; sm.attn.msh[2] = 0.f; }
    float vx = 0.f, vy = 0.f;
    __syncthreads();
    for (int blk = 0; blk < 8; ++blk) {
        const int l0 = ch * 256 + blk * 32;
        {
            const float* er = encf + ((size_t)b * LLEN + l0 + le) * HID + seg * 32;
            const float* us = sm.attn.u_s + seg * 32;
            float eacc = 0.f;
#pragma unroll
            for (int k = 0; k < 32; ++k) eacc += er[k] * us[k];
            sm.attn.accs[seg][le] = eacc;
        }
        __syncthreads();
        if (t < 32) {
            float e = 0.f;
#pragma unroll
            for (int s2 = 0; s2 < 16; ++s2) e += sm.attn.accs[s2][t];
            float bm = e;
#pragma unroll
            for (int off = 16; off > 0; off >>= 1) bm = fmaxf(bm, __shfl_xor(bm, off));
            const float m_old = sm.attn.msh[0];
            const float m_new = fmaxf(m_old, bm);
            const float wl = __expf(e - m_new);
            float sw = wl;
#pragma unroll
            for (int off = 16; off > 0; off >>= 1) sw += __shfl_xor(sw, off);
            sm.attn.w_s[t] = wl;
            if (t == 0) {
                const float sc = __expf(m_old - m_new);
                sm.attn.msh[2] = sc;
                sm.attn.msh[1] = sm.attn.msh[1] * sc + sw;
                sm.attn.msh[0] = m_new;
            }
        }
        __syncthreads();
        {
            const float sc = sm.attn.msh[2];
            vx *= sc; vy *= sc;
#pragma unroll
            for (int ll = 0; ll < 16; ++ll) {
                const int l = half * 16 + ll;
                const float wl = sm.attn.w_s[l];
                float2 f2 = *reinterpret_cast<const float2*>(encf + ((size_t)b * LLEN + l0 + l) * HID + 2 * col);
                vx += wl * f2.x; vy += wl * f2.y;
            }
        }
        __syncthreads();
    }
    if (half == 1) { sm.attn.u_s[2 * col] = vx; sm.attn.u_s[2 * col + 1] = vy; }
    __syncthreads();
    if (half == 0) {
        vx += sm.attn.u_s[2 * col];
        vy += sm.attn.u_s[2 * col + 1];
        const int pc = b * NCH + ch;
        vst1(pvB + (size_t)pc * HID + 2 * col,     vx);
        vst1(pvB + (size_t)pc * HID + 2 * col + 1, vy);
        if (t == 0) { vst1(pm + pc, sm.attn.msh[0]); vst1(ps + pc, sm.attn.msh[1]); }
    }
}

// ---------------------------------------------------------------------------
template<int USE16>
__global__ __launch_bounds__(NT, 1)
void k_seq(const float* __restrict__ xemb, const __half* __restrict__ enc16,
           const float* __restrict__ encf,
           const float* __restrict__ aWih, const float* __restrict__ aWhh,
           const float* __restrict__ abih, const float* __restrict__ abhh,
           const float* __restrict__ rWih, const float* __restrict__ rWhh,
           const float* __restrict__ rbih, const float* __restrict__ rbhh,
           const float* __restrict__ Pm, const float* __restrict__ p0v,
           const float* __restrict__ Whw, const float* __restrict__ Whb,
           const float* __restrict__ W1, const float* __restrict__ b1,
           const float* __restrict__ W2, const float* __restrict__ b2,
           float* h0, float* hs, float* ctxb,
           float* ub, float* chat, float* hid,
           float* pvB, float* pm, float* ps,
           float* out, unsigned* bar)
{
    __shared__ SMem sm;
    __shared__ float cPriv[3][128];
    __shared__ float hpartPriv[128];
    const int bid = blockIdx.x;
    const int i0  = bid * 2;
    const int t0  = threadIdx.x;
    if (t0 < 128) { cPriv[0][t0] = 0.f; cPriv[1][t0] = 0.f; cPriv[2][t0] = 0.f;
                    hpartPriv[t0] = 0.f; }
    __syncthreads();

    const float* W1row = W1 + (size_t)i0 * (2 * HID) + HID;  // FUSE rows (ctx half)
    unsigned nb = 0;

    for (int t = 0; t < SLEN; ++t) {
        const int par = t & 1;
        const float* h0r  = h0 + (size_t)par * BS * HID;
        float*       h0w  = h0 + (size_t)(par ^ 1) * BS * HID;
        const float* hs0r = hs + (size_t)(par * 2 + 0) * BS * HID;
        const float* hs1r = hs + (size_t)(par * 2 + 1) * BS * HID;
        float*       hs0w = hs + (size_t)((par ^ 1) * 2 + 0) * BS * HID;
        float*       hs1w = hs + (size_t)((par ^ 1) * 2 + 1) * BS * HID;

        // A: att-cell (+ fused hid(t-1) sharing the ctx segment)
        phase_cell<EMB, true, true>(sm, i0,
            xemb + (size_t)t * BS * EMB, ctxb, h0r,
            aWih, EMB + HID, aWhh, W1row, abih, abhh,
            cPriv[0], hpartPriv, h0w, hid);
        gridbar(bar, ++nb);
        // B: rnn layer 0
        phase_cell<HID, false, false>(sm, i0,
            h0w, nullptr, hs0r, rWih, HID, rWhh, nullptr, rbih, rbhh,
            cPriv[1], nullptr, hs0w, nullptr);
        gridbar(bar, ++nb);
        // C: rnn layer 1
        phase_cell<HID, false, false>(sm, i0,
            hs0w, nullptr, hs1r,
            rWih + (size_t)G4 * HID, HID, rWhh + (size_t)G4 * HID, nullptr,
            rbih + G4, rbhh + G4, cPriv[2], nullptr, hs1w, nullptr);
        gridbar(bar, ++nb);
        // D: logits(t-1) + dual GEMV (u -> ub, hpart -> LDS)
        if (t > 0) phase_logits(sm, bid, hid, W2, b2, out, t - 1);
        phase_dual(sm, i0, hs1w, Pm, p0v, W1, b1, ub, hpartPriv);
        gridbar(bar, ++nb);
        // E: attention partials
        if constexpr (USE16) phase_attn16(sm, bid, ub, enc16, pm, ps, pvB);
        else                 phase_attn32(sm, bid, ub, encf, pm, ps, pvB);
        gridbar(bar, ++nb);
        // F: combine -> chat
        phase_F(bid, pm, ps, pvB, chat);
        gridbar(bar, ++nb);
        // G: ctx = Whw@chat + Whb
        phase_lin2<false>(sm, i0, chat, Whw, HID, Whb, nullptr, ctxb);
        gridbar(bar, ++nb);
    }
    // tail: hid(S-1) = relu(hpart + W1b@ctx), then logits(S-1)
    phase_lin2<true>(sm, i0, ctxb, W1 + HID, 2 * HID, nullptr, hpartPriv, hid);
    gridbar(bar, ++nb);
    phase_logits(sm, bid, hid, W2, b2, out, SLEN - 1);
}

// ---------------------------------------------------------------------------
extern "C" void kernel_launch(void* const* d_in, const int* in_sizes, int n_in,
                              void* d_out, int out_size, void* d_ws, size_t ws_size,
                              hipStream_t stream)
{
    const int*   y    = (const int*)  d_in[0];
    const float* enc  = (const float*)d_in[1];
    const float* emb  = (const float*)d_in[2];
    const float* aWih = (const float*)d_in[3];
    const float* aWhh = (const float*)d_in[4];
    const float* abih = (const float*)d_in[5];
    const float* abhh = (const float*)d_in[6];
    const float* rWih = (const float*)d_in[7];
    const float* rWhh = (const float*)d_in[8];
    const float* rbih = (const float*)d_in[9];
    const float* rbhh = (const float*)d_in[10];
    const float* Wsw  = (const float*)d_in[11];
    const float* Wsb  = (const float*)d_in[12];
    const float* Whw  = (const float*)d_in[13];
    const float* Whb  = (const float*)d_in[14];
    const float* W1   = (const float*)d_in[15];
    const float* b1   = (const float*)d_in[16];
    const float* W2   = (const float*)d_in[17];
    const float* b2   = (const float*)d_in[18];
    float* out = (float*)d_out;

    unsigned* bar = (unsigned*)d_ws;
    float* p = (float*)((char*)d_ws + 4096);
    // zero region: h0 (2), hs (4), ctxb (1)  -> 7 x [64][512]
    float* h0   = p;  p += 2 * BS * HID;
    float* hs   = p;  p += 4 * BS * HID;
    float* ctxb = p;  p += BS * HID;
    float* zEnd = p;
    float* ub   = p;  p += BS * HID;
    float* chat = p;  p += BS * HID;
    float* hid  = p;  p += BS * HID;
    float* pvB  = p;  p += (size_t)BS * NCH * HID;
    float* pmb  = p;  p += 256;
    float* psb  = p;  p += 256;
    float* Pm   = p;  p += HID * HID;
    float* p0v  = p;  p += HID;
    float* xemb = p;  p += (size_t)SLEN * BS * EMB;
    __half* enc16 = (__half*)p;
    size_t need = (size_t)((char*)p - (char*)d_ws)
                + sizeof(__half) * (size_t)BS * LLEN * HID;
    const bool use16 = (ws_size >= need);

    hipMemsetAsync(bar, 0, 4096, stream);
    hipMemsetAsync(h0, 0, (size_t)(zEnd - h0) * sizeof(float), stream);

    k_embed<<<(SLEN * BS * EMB) / 256, 256, 0, stream>>>(y, emb, xemb);
    if (use16) k_cast<<<4096, 256, 0, stream>>>(enc, enc16, (BS * LLEN * HID) / 4);
    k_pmat<<<HID, 256, 0, stream>>>(Whw, Wsw, Wsb, Pm, p0v);

    if (use16)
        k_seq<1><<<NB, NT, 0, stream>>>(xemb, enc16, nullptr,
            aWih, aWhh, abih, abhh, rWih, rWhh, rbih, rbhh,
            Pm, p0v, Whw, Whb, W1, b1, W2, b2,
            h0, hs, ctxb, ub, chat, hid, pvB, pmb, psb, out, bar);
    else
        k_seq<0><<<NB, NT, 0, stream>>>(xemb, nullptr, enc,
            aWih, aWhh, abih, abhh, rWih, rWhh, rbih, rbhh,
            Pm, p0v, Whw, Whb, W1, b1, W2, b2,
            h0, hs, ctxb, ub, chat, hid, pvB, pmb, psb, out, bar);
}